// Round 7
// baseline (555.953 us; speedup 1.0000x reference)
//
#include <hip/hip_runtime.h>
#include <hip/hip_bf16.h>

typedef __hip_bfloat16 bf16;
typedef short bf16x8 __attribute__((ext_vector_type(8)));
typedef float f32x4 __attribute__((ext_vector_type(4)));

__device__ __forceinline__ float b2f(bf16 v) { return __bfloat162float(v); }
__device__ __forceinline__ void storev(float* p, float v) { *p = v; }
__device__ __forceinline__ void storev(bf16* p, float v) { *p = __float2bfloat16(v); }

// async global->LDS, 16B per lane. LDS dest must be wave base + lane*16.
__device__ __forceinline__ void gl2lds16(const bf16* g, bf16* l) {
  __builtin_amdgcn_global_load_lds(
      (const __attribute__((address_space(1))) unsigned int*)g,
      (__attribute__((address_space(3))) unsigned int*)l, 16, 0, 0);
}

// ---------------------------------------------------------------------------
// im2col: volume fp32 -> patch matrix bf16 [1024 tokens][512]
// ---------------------------------------------------------------------------
__global__ void im2col_kernel(const float* __restrict__ vol, bf16* __restrict__ out) {
  int t = blockIdx.x;
  int b = t >> 9, n = t & 511;
  int pd = n >> 6, ph = (n >> 3) & 7, pw = n & 7;
  const float* vb = vol + ((size_t)b << 18);
  for (int l = threadIdx.x; l < 512; l += 256) {
    int i = l >> 6, j = (l >> 3) & 7, k = l & 7;
    out[(size_t)t * 512 + l] =
        __float2bfloat16(vb[(pd * 8 + i) * 4096 + (ph * 8 + j) * 64 + (pw * 8 + k)]);
  }
}

__global__ void convert_kernel(const float* __restrict__ in, bf16* __restrict__ out, int n) {
  int i = (blockIdx.x * 256 + threadIdx.x) * 4;
  if (i + 3 < n) {
    float4 v = *(const float4*)&in[i];
    out[i + 0] = __float2bfloat16(v.x);
    out[i + 1] = __float2bfloat16(v.y);
    out[i + 2] = __float2bfloat16(v.z);
    out[i + 3] = __float2bfloat16(v.w);
  }
}

// ---------------------------------------------------------------------------
// Weight transpose+convert, ALL 4 layers: fp32 [R][C] -> bf16 [C][R].
// grid (1728, 4): y = layer. 64x64 tiles. bf16 in LDS (stride 68),
// b64 packed writes; read phase seg-swizzled -> conflict-free ds_read_u16.
// ---------------------------------------------------------------------------
__global__ __launch_bounds__(256) void transpose_all(
    const float* __restrict__ wqkv, const float* __restrict__ wo,
    const float* __restrict__ w1, const float* __restrict__ w2,
    bf16* __restrict__ tqkv, bf16* __restrict__ two,
    bf16* __restrict__ t1, bf16* __restrict__ t2) {
  int bid = blockIdx.x;
  size_t L = blockIdx.y;
  const float* in;
  bf16* out;
  int R, C, tc, t0;
  if (bid < 432)       { in = wqkv + L * 768 * 2304; out = tqkv + L * 768 * 2304; R = 768;  C = 2304; tc = 36; t0 = bid; }
  else if (bid < 576)  { in = wo + L * 768 * 768;    out = two + L * 768 * 768;   R = 768;  C = 768;  tc = 12; t0 = bid - 432; }
  else if (bid < 1152) { in = w1 + L * 768 * 3072;   out = t1 + L * 768 * 3072;   R = 768;  C = 3072; tc = 48; t0 = bid - 576; }
  else                 { in = w2 + L * 3072 * 768;   out = t2 + L * 3072 * 768;   R = 3072; C = 768;  tc = 12; t0 = bid - 1152; }
  int r0 = (t0 / tc) * 64, c0 = (t0 % tc) * 64;
  __shared__ bf16 Ts[64 * 68];
  int t = threadIdx.x;
  int r = t >> 4, cq = t & 15;
#pragma unroll
  for (int yy = 0; yy < 4; ++yy) {
    int row = r + yy * 16;
    float4 v = *(const float4*)&in[(size_t)(r0 + row) * C + c0 + cq * 4];
    bf16 pk[4] = {__float2bfloat16(v.x), __float2bfloat16(v.y),
                  __float2bfloat16(v.z), __float2bfloat16(v.w)};
    *(uint2*)&Ts[row * 68 + cq * 4] = *(uint2*)pk;
  }
  __syncthreads();
  int oc = t >> 2, seg = t & 3;
  bf16 pk[16];
#pragma unroll
  for (int j = 0; j < 16; ++j) {
    int e = (j + seg * 4) & 15;  // bank = (2j + 8*seg + oc/2)%32: conflict-free
    pk[e] = Ts[(seg * 16 + e) * 68 + oc];
  }
  *(uint4*)&out[(size_t)(c0 + oc) * R + r0 + seg * 16] = *(uint4*)&pk[0];
  *(uint4*)&out[(size_t)(c0 + oc) * R + r0 + seg * 16 + 8] = *(uint4*)&pk[8];
}

// ---------------------------------------------------------------------------
// LayerNorm (768): one wave per row, values in registers. grid 256 x 256.
// ---------------------------------------------------------------------------
template <typename OutT>
__global__ __launch_bounds__(256) void ln_kernel(const float* __restrict__ x,
                                                 const float* __restrict__ w,
                                                 const float* __restrict__ b,
                                                 OutT* __restrict__ out) {
  int row = blockIdx.x * 4 + (threadIdx.x >> 6);
  int lane = threadIdx.x & 63;
  const float* xr = x + (size_t)row * 768;
  float v[12];
  float s = 0.f, ss = 0.f;
#pragma unroll
  for (int i = 0; i < 12; ++i) {
    v[i] = xr[lane + i * 64];
    s += v[i];
    ss += v[i] * v[i];
  }
  for (int off = 32; off; off >>= 1) {
    s += __shfl_xor(s, off);
    ss += __shfl_xor(ss, off);
  }
  float m = s * (1.f / 768.f);
  float var = ss * (1.f / 768.f) - m * m;
  float rr = rsqrtf(var + 1e-5f);
#pragma unroll
  for (int i = 0; i < 12; ++i)
    storev(out + (size_t)row * 768 + lane + i * 64,
           (v[i] - m) * rr * w[lane + i * 64] + b[lane + i * 64]);
}

// ---------------------------------------------------------------------------
// MFMA bf16 GEMM (B^T layout), global_load_lds staging, unpadded SK=64.
// Wave grid 2x2; wave-tile (BM/2)x(BN/2).
// EPI: 0 plain->bf16 | 2 +bias,tanh->bf16 | 3 +bias+pos->f32
//      4 qkv split | 5 atomicAdd into f32 C (+bias when z==0)
// ---------------------------------------------------------------------------
template <int BM, int BN, int EPI>
__global__ __launch_bounds__(256) void mfma_gemm(
    const bf16* __restrict__ A, const bf16* __restrict__ Bt,
    const float* __restrict__ bias, const float* __restrict__ aux,
    bf16* __restrict__ vt,
    void* __restrict__ Cout, int M, int N, int K) {
  constexpr int WTM = BM / 2, WTN = BN / 2;
  constexpr int MT = WTM / 16, NT = WTN / 16;
  __shared__ bf16 As[BM * 64];
  __shared__ bf16 Bs[BN * 64];
  int tid = threadIdx.x;
  int wave = tid >> 6, lane = tid & 63;
  int wm = wave >> 1, wn = wave & 1;
  int m15 = lane & 15, q = lane >> 4;
  int m0 = blockIdx.y * BM, n0 = blockIdx.x * BN;
  int kspan = K / gridDim.z;
  int kbeg = blockIdx.z * kspan, kend = kbeg + kspan;

  f32x4 acc[MT][NT];
#pragma unroll
  for (int i = 0; i < MT; ++i)
#pragma unroll
    for (int j = 0; j < NT; ++j) acc[i][j] = (f32x4){0.f, 0.f, 0.f, 0.f};

  for (int k0 = kbeg; k0 < kend; k0 += 64) {
#pragma unroll
    for (int it = 0; it < BM * 8 / 256; ++it) {
      int c = tid + it * 256;
      int row = c >> 3, cc = c & 7;
      gl2lds16(&A[(size_t)(m0 + row) * K + k0 + cc * 8], &As[c * 8]);
    }
#pragma unroll
    for (int it = 0; it < BN * 8 / 256; ++it) {
      int c = tid + it * 256;
      int row = c >> 3, cc = c & 7;
      gl2lds16(&Bt[(size_t)(n0 + row) * K + k0 + cc * 8], &Bs[c * 8]);
    }
    __syncthreads();
#pragma unroll
    for (int s = 0; s < 2; ++s) {
      bf16x8 af[MT], bfr[NT];
#pragma unroll
      for (int i = 0; i < MT; ++i)
        af[i] = *(const bf16x8*)&As[(wm * WTM + i * 16 + m15) * 64 + s * 32 + q * 8];
#pragma unroll
      for (int j = 0; j < NT; ++j)
        bfr[j] = *(const bf16x8*)&Bs[(wn * WTN + j * 16 + m15) * 64 + s * 32 + q * 8];
#pragma unroll
      for (int i = 0; i < MT; ++i)
#pragma unroll
        for (int j = 0; j < NT; ++j)
          acc[i][j] = __builtin_amdgcn_mfma_f32_16x16x32_bf16(af[i], bfr[j], acc[i][j], 0, 0, 0);
    }
    __syncthreads();
  }

#pragma unroll
  for (int i = 0; i < MT; ++i) {
#pragma unroll
    for (int j = 0; j < NT; ++j) {
      int col = n0 + wn * WTN + j * 16 + m15;
      if (EPI == 4) {
        if (col < 1536) {
#pragma unroll
          for (int r = 0; r < 4; ++r) {
            int row = m0 + wm * WTM + i * 16 + q * 4 + r;
            ((bf16*)Cout)[(size_t)row * 1536 + col] = __float2bfloat16(acc[i][j][r]);
          }
        } else {
          int row0 = m0 + wm * WTM + i * 16 + q * 4;
          int cl = col - 1536;
          int hh = cl >> 6, dd = cl & 63;
          int bb = row0 >> 9, tok = row0 & 511;
          bf16 pk[4];
#pragma unroll
          for (int r = 0; r < 4; ++r) pk[r] = __float2bfloat16(acc[i][j][r]);
          *(uint2*)&vt[((size_t)(bb * 12 + hh) * 64 + dd) * 512 + tok] = *(uint2*)pk;
        }
      } else if (EPI == 5) {
        float bv = (blockIdx.z == 0) ? bias[col] : 0.f;
#pragma unroll
        for (int r = 0; r < 4; ++r) {
          int row = m0 + wm * WTM + i * 16 + q * 4 + r;
          unsafeAtomicAdd(&((float*)Cout)[(size_t)row * N + col], acc[i][j][r] + bv);
        }
      } else {
        float bv = (EPI == 0) ? 0.f : bias[col];
#pragma unroll
        for (int r = 0; r < 4; ++r) {
          int row = m0 + wm * WTM + i * 16 + q * 4 + r;
          float v = acc[i][j][r] + bv;
          if (EPI == 2) v = tanhf(v);
          if (EPI == 3) v += aux[(size_t)(row & 511) * N + col];
          if (EPI == 0 || EPI == 2)
            ((bf16*)Cout)[(size_t)row * N + col] = __float2bfloat16(v);
          else
            ((float*)Cout)[(size_t)row * N + col] = v;
        }
      }
    }
  }
}

// ---------------------------------------------------------------------------
// MFMA attention. Block = (b*12+h, 32-query tile), 128 thr = 2 waves.
// ---------------------------------------------------------------------------
__global__ __launch_bounds__(128) void attn_mfma(const bf16* __restrict__ qk,
                                                 const bf16* __restrict__ Vt,
                                                 bf16* __restrict__ o) {
  constexpr int PS = 520;
  __shared__ bf16 KVs[64 * 64];
  __shared__ bf16 P[32 * PS];
  int bh = blockIdx.x;
  int b = bh / 12, hh = bh % 12;
  int q0 = blockIdx.y * 32;
  int tid = threadIdx.x;
  int wave = tid >> 6, lane = tid & 63;
  int n15 = lane & 15, quad = lane >> 4;
  const bf16* qkb = qk + (size_t)b * 512 * 1536;
  int ql = wave * 16 + n15;

  const bf16* qp = qkb + (size_t)(q0 + ql) * 1536 + hh * 64 + quad * 8;
  bf16x8 qf0 = *(const bf16x8*)qp;
  bf16x8 qf1 = *(const bf16x8*)(qp + 32);

  f32x4 S[32];
#pragma unroll
  for (int i = 0; i < 32; ++i) S[i] = (f32x4){0.f, 0.f, 0.f, 0.f};

  const bf16* kbase = qkb + 768 + hh * 64;
#pragma unroll
  for (int kc = 0; kc < 8; ++kc) {
    __syncthreads();
#pragma unroll
    for (int it = 0; it < 4; ++it) {
      int c = tid + it * 128;
      int r = c >> 3, cc = c & 7;
      gl2lds16(&kbase[(size_t)(kc * 64 + r) * 1536 + cc * 8], &KVs[c * 8]);
    }
    __syncthreads();
#pragma unroll
    for (int t = 0; t < 4; ++t) {
      int idx = kc * 4 + t;
      bf16x8 a0 = *(const bf16x8*)&KVs[(t * 16 + n15) * 64 + quad * 8];
      bf16x8 a1 = *(const bf16x8*)&KVs[(t * 16 + n15) * 64 + 32 + quad * 8];
      S[idx] = __builtin_amdgcn_mfma_f32_16x16x32_bf16(a0, qf0, S[idx], 0, 0, 0);
      S[idx] = __builtin_amdgcn_mfma_f32_16x16x32_bf16(a1, qf1, S[idx], 0, 0, 0);
    }
  }

  float mx = -1e30f;
#pragma unroll
  for (int i = 0; i < 32; ++i)
#pragma unroll
    for (int r = 0; r < 4; ++r) { S[i][r] *= 0.125f; mx = fmaxf(mx, S[i][r]); }
  mx = fmaxf(mx, __shfl_xor(mx, 16));
  mx = fmaxf(mx, __shfl_xor(mx, 32));
  float sum = 0.f;
#pragma unroll
  for (int i = 0; i < 32; ++i)
#pragma unroll
    for (int r = 0; r < 4; ++r) { float e = __expf(S[i][r] - mx); S[i][r] = e; sum += e; }
  sum += __shfl_xor(sum, 16);
  sum += __shfl_xor(sum, 32);
  float inv = 1.f / sum;

#pragma unroll
  for (int i = 0; i < 32; ++i) {
    bf16 pk[4];
#pragma unroll
    for (int r = 0; r < 4; ++r) pk[r] = __float2bfloat16(S[i][r] * inv);
    *(uint2*)&P[(size_t)ql * PS + i * 16 + quad * 4] = *(uint2*)pk;
  }

  f32x4 oacc[4];
#pragma unroll
  for (int dt = 0; dt < 4; ++dt) oacc[dt] = (f32x4){0.f, 0.f, 0.f, 0.f};
  const bf16* vtb = Vt + (size_t)bh * 64 * 512;
  for (int kc = 0; kc < 8; ++kc) {
    __syncthreads();
#pragma unroll
    for (int it = 0; it < 4; ++it) {
      int c = tid + it * 128;
      int r = c >> 3, cc = c & 7;
      gl2lds16(&vtb[(size_t)r * 512 + kc * 64 + cc * 8], &KVs[c * 8]);
    }
    __syncthreads();
    bf16x8 p0 = *(const bf16x8*)&P[(size_t)ql * PS + kc * 64 + quad * 8];
    bf16x8 p1 = *(const bf16x8*)&P[(size_t)ql * PS + kc * 64 + 32 + quad * 8];
#pragma unroll
    for (int dt = 0; dt < 4; ++dt) {
      bf16x8 v0 = *(const bf16x8*)&KVs[(dt * 16 + n15) * 64 + quad * 8];
      bf16x8 v1 = *(const bf16x8*)&KVs[(dt * 16 + n15) * 64 + 32 + quad * 8];
      oacc[dt] = __builtin_amdgcn_mfma_f32_16x16x32_bf16(p0, v0, oacc[dt], 0, 0, 0);
      oacc[dt] = __builtin_amdgcn_mfma_f32_16x16x32_bf16(p1, v1, oacc[dt], 0, 0, 0);
    }
  }

#pragma unroll
  for (int dt = 0; dt < 4; ++dt)
#pragma unroll
    for (int r = 0; r < 4; ++r) {
      int tok = q0 + wave * 16 + quad * 4 + r;
      o[((size_t)b * 512 + tok) * 768 + hh * 64 + dt * 16 + n15] =
          __float2bfloat16(oacc[dt][r]);
    }
}

// ---------------------------------------------------------------------------
extern "C" void kernel_launch(void* const* d_in, const int* in_sizes, int n_in,
                              void* d_out, int out_size, void* d_ws, size_t ws_size,
                              hipStream_t stream) {
  const float* volume = (const float*)d_in[0];
  const float* conv_w = (const float*)d_in[1];
  const float* conv_b = (const float*)d_in[2];
  const float* pos    = (const float*)d_in[3];
  const float* ln1w   = (const float*)d_in[4];
  const float* ln1b   = (const float*)d_in[5];
  const float* wqkv   = (const float*)d_in[6];
  const float* wo     = (const float*)d_in[7];
  const float* bo     = (const float*)d_in[8];
  const float* ln2w   = (const float*)d_in[9];
  const float* ln2b   = (const float*)d_in[10];
  const float* w1     = (const float*)d_in[11];
  const float* b1     = (const float*)d_in[12];
  const float* w2     = (const float*)d_in[13];
  const float* b2     = (const float*)d_in[14];
  const float* lnfw   = (const float*)d_in[15];
  const float* lnfb   = (const float*)d_in[16];

  // ws layout (~73 MB)
  char* w = (char*)d_ws;
  float* x    = (float*)(w + 0);           // fp32 residual [1024][768]
  bf16* h     = (bf16*)(w + 3145728);      // ln out [1024][768]
  bf16* qk    = (bf16*)(w + 4718592);      // Q|K [1024][1536]; aliases patchA
  bf16* patchA= qk;                        // im2col [1024][512]
  bf16* Vt    = (bf16*)(w + 7864320);      // V^T [24][64][512]
  bf16* oact  = (bf16*)(w + 9437184);      // attn-o / mlp act [1024][3072]
  bf16* cwb   = (bf16*)(w + 15728640);     // conv_w bf16 [768][512]
  bf16* tqkv  = (bf16*)(w + 16515072);     // 4 x [2304][768]
  bf16* two   = (bf16*)(w + 30670848);     // 4 x [768][768]
  bf16* t1    = (bf16*)(w + 35389440);     // 4 x [3072][768]
  bf16* t2    = (bf16*)(w + 54263808);     // 4 x [768][3072]

  convert_kernel<<<384, 256, 0, stream>>>(conv_w, cwb, 768 * 512);
  im2col_kernel<<<1024, 256, 0, stream>>>(volume, patchA);
  transpose_all<<<dim3(1728, 4), 256, 0, stream>>>(wqkv, wo, w1, w2, tqkv, two, t1, t2);
  mfma_gemm<64, 64, 3><<<dim3(12, 16), 256, 0, stream>>>(
      patchA, cwb, conv_b, pos, nullptr, x, 1024, 768, 512);

  for (int L = 0; L < 4; ++L) {
    ln_kernel<bf16><<<256, 256, 0, stream>>>(x, ln1w + L * 768, ln1b + L * 768, h);
    mfma_gemm<128, 64, 4><<<dim3(36, 8), 256, 0, stream>>>(
        h, tqkv + (size_t)L * 768 * 2304, nullptr, nullptr, Vt, qk, 1024, 2304, 768);
    attn_mfma<<<dim3(24, 16), 128, 0, stream>>>(qk, Vt, oact);
    mfma_gemm<64, 64, 5><<<dim3(12, 16, 2), 256, 0, stream>>>(
        oact, two + (size_t)L * 768 * 768, bo + L * 768, nullptr, nullptr, x, 1024, 768, 768);
    ln_kernel<bf16><<<256, 256, 0, stream>>>(x, ln2w + L * 768, ln2b + L * 768, h);
    mfma_gemm<128, 64, 2><<<dim3(48, 8), 256, 0, stream>>>(
        h, t1 + (size_t)L * 768 * 3072, b1 + L * 3072, nullptr, nullptr, oact, 1024, 3072, 768);
    mfma_gemm<64, 64, 5><<<dim3(12, 16, 4), 256, 0, stream>>>(
        oact, t2 + (size_t)L * 768 * 3072, b2 + L * 768, nullptr, nullptr, x, 1024, 768, 3072);
  }

  ln_kernel<float><<<256, 256, 0, stream>>>(x, lnfw, lnfb, (float*)d_out);
}